// Round 9
// baseline (250.142 us; speedup 1.0000x reference)
//
#include <hip/hip_runtime.h>

#define NROWS 32768
#define NE    1024
#define ED    64

typedef float4 f4;

// ---------------------------------------------------------------------------
// Prep: eTi[k4][code] = f4(cb[code][4k4..4k4+3]) (k4-blocked transpose,
// coalesced writes) + ssq[code] with numpy pairwise-8 op order.
// ---------------------------------------------------------------------------
__global__ void vq_prep(const float* __restrict__ cb, f4* __restrict__ eTi,
                        float* __restrict__ ssq)
{
    int j = blockIdx.x * blockDim.x + threadIdx.x;   // 0..1023 code id
    const f4* crow = (const f4*)(cb + (size_t)j * ED);
    f4 v[16];
#pragma unroll
    for (int i = 0; i < 16; ++i) v[i] = crow[i];
    {
#pragma clang fp contract(off)
        float r0 = v[0].x*v[0].x, r1 = v[0].y*v[0].y;
        float r2 = v[0].z*v[0].z, r3 = v[0].w*v[0].w;
        float r4 = v[1].x*v[1].x, r5 = v[1].y*v[1].y;
        float r6 = v[1].z*v[1].z, r7 = v[1].w*v[1].w;
#pragma unroll
        for (int q = 2; q < 16; q += 2) {
            r0 += v[q].x*v[q].x;   r1 += v[q].y*v[q].y;
            r2 += v[q].z*v[q].z;   r3 += v[q].w*v[q].w;
            r4 += v[q+1].x*v[q+1].x; r5 += v[q+1].y*v[q+1].y;
            r6 += v[q+1].z*v[q+1].z; r7 += v[q+1].w*v[q+1].w;
        }
        ssq[j] = ((r0+r1)+(r2+r3)) + ((r4+r5)+(r6+r7));
    }
#pragma unroll
    for (int k4 = 0; k4 < 16; ++k4) eTi[(size_t)k4 * NE + j] = v[k4];
}

// ---------------------------------------------------------------------------
// Main: no LDS staging, no barriers in the scan.
//  - block: 16 rows, 4 waves. wave w: rowgroup rg=w>>1 (8 rows), code-half
//    h=w&1 (512 codes). 8192 waves total -> 8 waves/SIMD grid-resident.
//  - per k4: 1 coalesced global_load_dwordx4 (lane's code, 4 dims; vmcnt)
//            + 8 wave-uniform s_load_dwordx4 z fragments (lgkmcnt, SMEM only)
//            + 32 wave-FMAs. Counters independent -> clean pipelining.
// Numerics identical to passing r3/r6/r7: cn/ssq numpy pairwise-8; dot
// ascending-k single-acc fmaf; d = fl(fl(cn+ssq) - 2*acc); first-index
// argmin (strict < over ascending g per lane, lex (d,idx) across lanes
// and across the two halves).
// ---------------------------------------------------------------------------
__global__ __launch_bounds__(256, 8)
void vq_main(const float* __restrict__ z, const float* __restrict__ cb,
             const f4* __restrict__ eTi, const float* __restrict__ ssq,
             float* __restrict__ out, float* __restrict__ partials)
{
    __shared__ float cvsh[4][8];
    __shared__ int   cish[4][8];
    __shared__ int   idxsh[16];
    __shared__ float redsh[4];

    const int tid  = threadIdx.x;
    const int lane = tid & 63;
    const int w    = tid >> 6;                      // wave 0..3
    const int w_u  = __builtin_amdgcn_readfirstlane(w);
    const int rg   = w_u >> 1;                      // row group (uniform)
    const int half = w_u & 1;                       // code half (uniform)
    const int rowbase = blockIdx.x * 16;

    const float* zw = z + (size_t)(rowbase + rg * 8) * ED;  // scalar base

    // ---- row norms for this wave's 8 rows, numpy pairwise-8 ----
    float cn[8];
    {
        const int rl = lane >> 3;            // row within group
        const int jj = lane & 7;             // accumulator index
        const float* zr = zw + (size_t)rl * ED;
        float a;
        {
#pragma clang fp contract(off)
            a = 0.f;
#pragma unroll
            for (int i = 0; i < 8; ++i) { float v = zr[8*i + jj]; a += v*v; }
        }
        a += __shfl_xor(a, 1);
        a += __shfl_xor(a, 2);
        a += __shfl_xor(a, 4);
#pragma unroll
        for (int r = 0; r < 8; ++r) cn[r] = __shfl(a, r * 8);
    }

    float bestv[8];
    int   besti[8];
#pragma unroll
    for (int r = 0; r < 8; ++r) { bestv[r] = INFINITY; besti[r] = 0; }

    // ---- scan this wave's 512 codes in 8 groups of 64 (code = base+lane) ----
    for (int g = 0; g < 8; ++g) {
        const int cb0 = half * 512 + g * 64;        // uniform group base
        const int c   = cb0 + lane;                 // this lane's code
        const float sq = ssq[c];                    // coalesced

        float acc[8];
#pragma unroll
        for (int r = 0; r < 8; ++r) acc[r] = 0.f;

#pragma unroll 4
        for (int k4 = 0; k4 < 16; ++k4) {
            f4 e  = eTi[(size_t)k4 * NE + c];       // coalesced dwordx4 (vmcnt)
            f4 z0 = *(const f4*)(zw + 0*ED + 4*k4); // s_load_dwordx4 (lgkmcnt)
            f4 z1 = *(const f4*)(zw + 1*ED + 4*k4);
            f4 z2 = *(const f4*)(zw + 2*ED + 4*k4);
            f4 z3 = *(const f4*)(zw + 3*ED + 4*k4);
            f4 z4 = *(const f4*)(zw + 4*ED + 4*k4);
            f4 z5 = *(const f4*)(zw + 5*ED + 4*k4);
            f4 z6 = *(const f4*)(zw + 6*ED + 4*k4);
            f4 z7 = *(const f4*)(zw + 7*ED + 4*k4);
#define ROWFMA(r, zz)                                 \
            acc[r] = fmaf(e.x, zz.x, acc[r]);         \
            acc[r] = fmaf(e.y, zz.y, acc[r]);         \
            acc[r] = fmaf(e.z, zz.z, acc[r]);         \
            acc[r] = fmaf(e.w, zz.w, acc[r]);
            ROWFMA(0, z0) ROWFMA(1, z1) ROWFMA(2, z2) ROWFMA(3, z3)
            ROWFMA(4, z4) ROWFMA(5, z5) ROWFMA(6, z6) ROWFMA(7, z7)
#undef ROWFMA
        }

        {
#pragma clang fp contract(off)
#pragma unroll
            for (int r = 0; r < 8; ++r) {
                float t1 = cn[r] + sq;
                float d  = t1 - 2.0f * acc[r];       // 2*acc exact
                if (d < bestv[r]) { bestv[r] = d; besti[r] = c; }
            }
        }
    }

    // ---- cross-lane lexicographic (val, idx) argmin per row ----
#pragma unroll
    for (int r = 0; r < 8; ++r) {
        float v = bestv[r];
        int   i = besti[r];
#pragma unroll
        for (int m = 1; m < 64; m <<= 1) {
            float ov = __shfl_xor(v, m);
            int   oi = __shfl_xor(i, m);
            if (ov < v || (ov == v && oi < i)) { v = ov; i = oi; }
        }
        if (lane == 0) { cvsh[w][r] = v; cish[w][r] = i; }
    }
    __syncthreads();

    // ---- combine the two code-halves per row; store idx ----
    if (tid < 16) {
        const int r  = tid & 7;
        const int g2 = tid >> 3;                    // row group
        float v0 = cvsh[g2*2][r];   int i0 = cish[g2*2][r];
        float v1 = cvsh[g2*2+1][r]; int i1 = cish[g2*2+1][r];
        int ii = (v1 < v0 || (v1 == v0 && i1 < i0)) ? i1 : i0;
        ii &= (NE - 1);                             // defensive no-op
        idxsh[tid] = ii;
        out[(size_t)NROWS * ED + rowbase + tid] = (float)ii;
    }
    __syncthreads();

    // ---- epilogue: thread -> (row = tid>>4, f4-col = tid&15) ----
    const int erow = tid >> 4;
    const int q4   = tid & 15;
    const int gi   = idxsh[erow];
    f4 e  = *(const f4*)(cb + (size_t)gi * ED + q4 * 4);
    f4 zz = *(const f4*)(z + (size_t)(rowbase + erow) * ED + q4 * 4);
    float lp;
    f4 o;
    {
#pragma clang fp contract(off)
        float d0 = e.x - zz.x; o.x = zz.x + d0;
        float d1 = e.y - zz.y; o.y = zz.y + d1;
        float d2 = e.z - zz.z; o.z = zz.z + d2;
        float d3 = e.w - zz.w; o.w = zz.w + d3;
        lp = ((d0*d0 + d1*d1) + (d2*d2 + d3*d3));
    }
    *(f4*)(out + (size_t)(rowbase + erow) * ED + q4 * 4) = o;

    // ---- deterministic loss partial ----
#pragma unroll
    for (int m = 1; m < 64; m <<= 1) lp += __shfl_xor(lp, m);
    if (lane == 0) redsh[w] = lp;
    __syncthreads();
    if (tid == 0)
        partials[blockIdx.x] = (redsh[0] + redsh[1]) + (redsh[2] + redsh[3]);
}

// ---------------------------------------------------------------------------
// Finalize: deterministic tree-sum of 2048 partials -> loss scalar (f32)
// ---------------------------------------------------------------------------
__global__ void vq_finalize(const float* __restrict__ partials,
                            float* __restrict__ out)
{
    __shared__ float red[256];
    int t = threadIdx.x;
    float a = (partials[t]        + partials[t + 256])
            + (partials[t + 512]  + partials[t + 768]);
    float b = (partials[t + 1024] + partials[t + 1280])
            + (partials[t + 1536] + partials[t + 1792]);
    red[t] = a + b;
    __syncthreads();
    for (int m = 128; m > 0; m >>= 1) {
        if (t < m) red[t] += red[t + m];
        __syncthreads();
    }
    if (t == 0) {
        float mean = red[0] / (float)((size_t)NROWS * ED);
        out[(size_t)NROWS * ED + NROWS] = mean + 0.25f * mean;  // (1+BETA)*mean
    }
}

extern "C" void kernel_launch(void* const* d_in, const int* in_sizes, int n_in,
                              void* d_out, int out_size, void* d_ws, size_t ws_size,
                              hipStream_t stream)
{
    (void)in_sizes; (void)n_in; (void)out_size; (void)ws_size;
    const float* z  = (const float*)d_in[0];
    const float* cb = (const float*)d_in[1];
    float* out = (float*)d_out;

    f4*    eTi      = (f4*)d_ws;                     // 16*1024 f4 = 256 KB
    float* ssq      = (float*)d_ws + 16 * NE * 4;    // 1024 f32
    float* partials = ssq + NE;                      // 2048 f32

    vq_prep<<<4, 256, 0, stream>>>(cb, eTi, ssq);
    vq_main<<<2048, 256, 0, stream>>>(z, cb, eTi, ssq, out, partials);
    vq_finalize<<<1, 256, 0, stream>>>(partials, out);
}

// Round 10
// 94.162 us; speedup vs baseline: 2.6565x; 2.6565x over previous
//
#include <hip/hip_runtime.h>

#define NROWS 32768
#define NE    1024
#define ED    64
#define CHUNK 64               // codes per LDS chunk (16 KB as [k4][code] f4)
#define NCH   (NE / CHUNK)     // 16 chunks
#define RPW   4                // rows per wave
#define NW    4                // waves per block
#define RPB   (RPW * NW)       // 16 rows per block

typedef float4 f4;

// ---------------------------------------------------------------------------
// Prep: per-code ||e||^2 with numpy pairwise-8 op order (exact f32 replication)
// ---------------------------------------------------------------------------
__global__ void vq_prep(const float* __restrict__ cb, float* __restrict__ ssq)
{
    int j = blockIdx.x * blockDim.x + threadIdx.x;   // 0..1023
    const f4* crow = (const f4*)(cb + (size_t)j * ED);
    f4 v[16];
#pragma unroll
    for (int i = 0; i < 16; ++i) v[i] = crow[i];
    {
#pragma clang fp contract(off)
        float r0 = v[0].x*v[0].x, r1 = v[0].y*v[0].y;
        float r2 = v[0].z*v[0].z, r3 = v[0].w*v[0].w;
        float r4 = v[1].x*v[1].x, r5 = v[1].y*v[1].y;
        float r6 = v[1].z*v[1].z, r7 = v[1].w*v[1].w;
#pragma unroll
        for (int q = 2; q < 16; q += 2) {
            r0 += v[q].x*v[q].x;     r1 += v[q].y*v[q].y;
            r2 += v[q].z*v[q].z;     r3 += v[q].w*v[q].w;
            r4 += v[q+1].x*v[q+1].x; r5 += v[q+1].y*v[q+1].y;
            r6 += v[q+1].z*v[q+1].z; r7 += v[q+1].w*v[q+1].w;
        }
        ssq[j] = ((r0+r1)+(r2+r3)) + ((r4+r5)+(r6+r7));
    }
}

// ---------------------------------------------------------------------------
// Main (r7 inner-loop family, sized for true 8 waves/SIMD):
//  - 2048 blocks x 256 thr; block = 16 rows; wave = 4 rows (disjoint).
//  - chunk = 64 codes in LDS as eL4[k4][code] (f4 of dims 4k4..4k4+3):
//    inner k4 = 1 conflict-free ds_read_b128 + 4 wave-uniform s_load_dwordx4
//    (z fragments) + 16 FMAs. Per-lane state ~35 VGPR -> no spill at the
//    64-reg occupancy cap.
// Numerics identical per row to passing r3/r6/r7: cn/ssq numpy pairwise-8;
// dot ascending-k single-acc fmaf; d = fl(fl(cn+ssq)-2*acc); first-index
// argmin (strict < over ascending j per lane, lex (d,idx) butterfly).
// ---------------------------------------------------------------------------
__global__ __launch_bounds__(256, 8)
void vq_main(const float* __restrict__ z, const float* __restrict__ cb,
             const float* __restrict__ ssq, float* __restrict__ out,
             float* __restrict__ partials)
{
    __shared__ __align__(16) f4 eL4[16 * CHUNK];     // 16 KB: [k4][code]
    __shared__ int   idxsh[RPB];
    __shared__ float redsh[NW];

    const int tid  = threadIdx.x;
    const int lane = tid & 63;
    const int w    = tid >> 6;                       // wave 0..3
    const int w_u  = __builtin_amdgcn_readfirstlane(w);
    const int rowbase = blockIdx.x * RPB;

    const float* zw = z + (size_t)(rowbase + w_u * RPW) * ED;  // scalar base

    // ---- row norms for this wave's 4 rows, numpy pairwise-8 ----
    float cn[RPW];
    {
        const int rl = (lane >> 3) & 3;      // row within wave's 4 (dup hi lanes)
        const int jj = lane & 7;             // accumulator index
        const float* zr = zw + (size_t)rl * ED;
        float a;
        {
#pragma clang fp contract(off)
            a = 0.f;
#pragma unroll
            for (int i = 0; i < 8; ++i) { float v = zr[8*i + jj]; a += v*v; }
        }
        a += __shfl_xor(a, 1);
        a += __shfl_xor(a, 2);
        a += __shfl_xor(a, 4);
#pragma unroll
        for (int r = 0; r < RPW; ++r) cn[r] = __shfl(a, r * 8);
    }

    float bestv[RPW];
    int   besti[RPW];
#pragma unroll
    for (int r = 0; r < RPW; ++r) { bestv[r] = INFINITY; besti[r] = 0; }

    for (int ch = 0; ch < NCH; ++ch) {
        __syncthreads();   // previous chunk's readers done
        // ---- stage chunk: thread (c = tid&63, h = tid>>6) stages 16 dims ----
        {
            const int c = tid & 63;
            const int h = tid >> 6;
            const f4* crow = (const f4*)(cb + (size_t)(ch * CHUNK + c) * ED
                                         + h * 16);
#pragma unroll
            for (int i = 0; i < 4; ++i)
                eL4[(4*h + i) * CHUNK + c] = crow[i];   // conflict-free b128
        }
        __syncthreads();

        const float sq = ssq[ch * CHUNK + lane];     // coalesced, L2-hot

        float acc[RPW];
#pragma unroll
        for (int r = 0; r < RPW; ++r) acc[r] = 0.f;

#pragma unroll 4
        for (int k4 = 0; k4 < 16; ++k4) {
            f4 e  = eL4[k4 * CHUNK + lane];          // 1 ds_read_b128
            f4 z0 = *(const f4*)(zw + 0*ED + 4*k4);  // s_load_dwordx4 (SMEM)
            f4 z1 = *(const f4*)(zw + 1*ED + 4*k4);
            f4 z2 = *(const f4*)(zw + 2*ED + 4*k4);
            f4 z3 = *(const f4*)(zw + 3*ED + 4*k4);
#define ROWFMA(r, zz)                                 \
            acc[r] = fmaf(e.x, zz.x, acc[r]);         \
            acc[r] = fmaf(e.y, zz.y, acc[r]);         \
            acc[r] = fmaf(e.z, zz.z, acc[r]);         \
            acc[r] = fmaf(e.w, zz.w, acc[r]);
            ROWFMA(0, z0) ROWFMA(1, z1) ROWFMA(2, z2) ROWFMA(3, z3)
#undef ROWFMA
        }

        {
#pragma clang fp contract(off)
#pragma unroll
            for (int r = 0; r < RPW; ++r) {
                float t1 = cn[r] + sq;
                float d  = t1 - 2.0f * acc[r];       // 2*acc exact
                int j = ch * CHUNK + lane;
                if (d < bestv[r]) { bestv[r] = d; besti[r] = j; }
            }
        }
    }

    // ---- cross-lane lexicographic (val, idx) argmin per row ----
#pragma unroll
    for (int r = 0; r < RPW; ++r) {
        float v = bestv[r];
        int   i = besti[r];
#pragma unroll
        for (int m = 1; m < 64; m <<= 1) {
            float ov = __shfl_xor(v, m);
            int   oi = __shfl_xor(i, m);
            if (ov < v || (ov == v && oi < i)) { v = ov; i = oi; }
        }
        if (lane == 0) idxsh[w * RPW + r] = i & (NE - 1);
    }
    __syncthreads();

    // ---- uniform coalesced idx store (f32) ----
    if (tid < RPB)
        out[(size_t)NROWS * ED + rowbase + tid] = (float)idxsh[tid];

    // ---- epilogue: thread -> (row = tid>>4, f4-col = tid&15) ----
    const int erow = tid >> 4;
    const int q4   = tid & 15;
    const int gi   = idxsh[erow];
    f4 e  = *(const f4*)(cb + (size_t)gi * ED + q4 * 4);
    f4 zz = *(const f4*)(z + (size_t)(rowbase + erow) * ED + q4 * 4);
    float lp;
    f4 o;
    {
#pragma clang fp contract(off)
        float d0 = e.x - zz.x; o.x = zz.x + d0;
        float d1 = e.y - zz.y; o.y = zz.y + d1;
        float d2 = e.z - zz.z; o.z = zz.z + d2;
        float d3 = e.w - zz.w; o.w = zz.w + d3;
        lp = ((d0*d0 + d1*d1) + (d2*d2 + d3*d3));
    }
    *(f4*)(out + (size_t)(rowbase + erow) * ED + q4 * 4) = o;

    // ---- deterministic loss partial ----
#pragma unroll
    for (int m = 1; m < 64; m <<= 1) lp += __shfl_xor(lp, m);
    if (lane == 0) redsh[w] = lp;
    __syncthreads();
    if (tid == 0)
        partials[blockIdx.x] = (redsh[0] + redsh[1]) + (redsh[2] + redsh[3]);
}

// ---------------------------------------------------------------------------
// Finalize: deterministic tree-sum of 2048 partials -> loss scalar (f32)
// ---------------------------------------------------------------------------
__global__ void vq_finalize(const float* __restrict__ partials,
                            float* __restrict__ out)
{
    __shared__ float red[256];
    int t = threadIdx.x;
    float a = (partials[t]        + partials[t + 256])
            + (partials[t + 512]  + partials[t + 768]);
    float b = (partials[t + 1024] + partials[t + 1280])
            + (partials[t + 1536] + partials[t + 1792]);
    red[t] = a + b;
    __syncthreads();
    for (int m = 128; m > 0; m >>= 1) {
        if (t < m) red[t] += red[t + m];
        __syncthreads();
    }
    if (t == 0) {
        float mean = red[0] / (float)((size_t)NROWS * ED);
        out[(size_t)NROWS * ED + NROWS] = mean + 0.25f * mean;  // (1+BETA)*mean
    }
}

extern "C" void kernel_launch(void* const* d_in, const int* in_sizes, int n_in,
                              void* d_out, int out_size, void* d_ws, size_t ws_size,
                              hipStream_t stream)
{
    (void)in_sizes; (void)n_in; (void)out_size; (void)ws_size;
    const float* z  = (const float*)d_in[0];
    const float* cb = (const float*)d_in[1];
    float* out = (float*)d_out;
    float* ssq      = (float*)d_ws;          // 1024 f32
    float* partials = ssq + NE;              // 2048 f32

    vq_prep<<<4, 256, 0, stream>>>(cb, ssq);
    vq_main<<<2048, 256, 0, stream>>>(z, cb, ssq, out, partials);
    vq_finalize<<<1, 256, 0, stream>>>(partials, out);
}